// Round 7
// baseline (206.640 us; speedup 1.0000x reference)
//
#include <hip/hip_runtime.h>

// Problem constants (fixed by setup_inputs)
#define NNODES 50000
#define NEDGES 800000
#define DIM    128
#define NRELS  4          // edge relations; weight slice 4 = self-loop
#define NBLK2  25         // scan chunks: 25*2048 = 51200 >= NNODES+1
#define DBLK   128        // k_dfill dense blocks per rel (r2 mapping)
#define NDB    (4*DBLK)   // 512 dense blocks (self-loop lives in k_agg)
#define NFB    3125       // fill blocks
#define EPB    12500      // edges per hist chunk
#define NHC    64         // hist chunks (NHC*EPB == NEDGES)
#define RNG    25000      // dst bins per hist range-block (2 ranges cover NNODES)
#define NPB    782        // prep blocks in k_ph (782*1024 >= 800000)

typedef __attribute__((ext_vector_type(8))) short bf16x8;
typedef __attribute__((ext_vector_type(8))) unsigned short u16x8;
typedef __attribute__((ext_vector_type(4))) float f32x4;

// ---- ws layout (bytes) ----
#define SSRC_OFF 0             // u32[NEDGES]: rowcode = rel*NNODES+src, dst-sorted  3,200,000
#define CNT_OFF  3200000       // u32[51200] dst histogram excl scan                   204,800
#define BSUM_OFF 3404800       // u32[64]                                                  256
#define RANK_OFF 3405056       // u16[NEDGES] within-(chunk,dst) rank                1,600,000
#define PCNT_OFF 5005056       // u16[NHC][NNODES] per-chunk hist -> excl col-scan   6,400,000
#define WT_OFF   11405056      // bf16[5*128*128] W^T                                  163,840
#define XBF_OFF  11568896      // bf16[NNODES*DIM]                                  12,800,000
#define H_OFF    24368896      // bf16[4*NNODES*128] per-rel transforms             51,200,000
                               // total ~75.6 MB

__device__ __forceinline__ unsigned short f2bf(float f) {  // RNE f32->bf16
  unsigned u = __float_as_uint(f);
  return (unsigned short)((u + 0x7FFFu + ((u >> 16) & 1u)) >> 16);
}

// ---- FUSED prep + hist (independent roles, disjoint block ranges, co-scheduled):
// Blocks [0, NHC*2): LDS-privatized per-chunk dst histogram + within-chunk rank.
//   25000 bins/range packed 2 x u16 per u32 = 50KB LDS; low field max 12500 so the
//   packed add never carries across fields. No global atomics.
// Blocks [NHC*2, +NPB): x f32->bf16 convert, W transpose+convert (pure BW).
__global__ __launch_bounds__(1024) void k_ph(
    const float* __restrict__ x, unsigned short* __restrict__ xbf,
    const float* __restrict__ W, unsigned short* __restrict__ Wt,
    const int* __restrict__ dst, unsigned short* __restrict__ rank,
    unsigned short* __restrict__ pcnt) {
  __shared__ unsigned lh[RNG / 2];  // 12500 u32 = 50,000 B
  if (blockIdx.x < NHC * 2) {
    int c = blockIdx.x >> 1;
    int r0 = (blockIdx.x & 1) * RNG;
    for (int i = threadIdx.x; i < RNG / 2; i += 1024) lh[i] = 0u;
    __syncthreads();
    int e0 = c * EPB;
    for (int e = e0 + threadIdx.x; e < e0 + EPB; e += 1024) {
      int d = dst[e] - r0;
      if ((unsigned)d < (unsigned)RNG) {
        unsigned old = atomicAdd(&lh[d >> 1], (d & 1) ? 65536u : 1u);
        rank[e] = (unsigned short)((old >> ((d & 1) << 4)) & 0xFFFFu);
      }
    }
    __syncthreads();
    // dump packed u16 pairs: exactly the u16[RNG] slice of row c at offset r0
    unsigned* prow = (unsigned*)(pcnt + (size_t)c * NNODES + r0);
    for (int i = threadIdx.x; i < RNG / 2; i += 1024) prow[i] = lh[i];
    return;
  }
  int i = (blockIdx.x - NHC * 2) * 1024 + threadIdx.x;
  if (i < NNODES * DIM / 8) {
    const float4* p = (const float4*)x + i * 2;
    float4 v0 = p[0], v1 = p[1];
    u16x8 o;
    o[0] = f2bf(v0.x); o[1] = f2bf(v0.y); o[2] = f2bf(v0.z); o[3] = f2bf(v0.w);
    o[4] = f2bf(v1.x); o[5] = f2bf(v1.y); o[6] = f2bf(v1.z); o[7] = f2bf(v1.w);
    *(u16x8*)(xbf + i * 8) = o;
  }
  if (i < 5 * DIM * DIM) {
    int r = i >> 14, rem = i & 16383, k = rem >> 7, c = rem & 127;
    Wt[(r << 14) + (c << 7) + k] = f2bf(W[i]);
  }
}

// ---- wide column-scan: one bin per thread over the NHC chunk rows, in place ->
// exclusive chunk prefix; bin total -> cnt[d]. Bins >= NNODES zeroed so the
// downstream total-scan sees clean tails.
__global__ void k_scanC(unsigned short* __restrict__ pcnt, unsigned* __restrict__ cnt) {
  int d = blockIdx.x * 256 + threadIdx.x;  // grid 200*256 = 51200 exact
  if (d < NNODES) {
    unsigned run = 0;
#pragma unroll 8
    for (int b = 0; b < NHC; b++) {
      size_t off = (size_t)b * NNODES + d;
      unsigned v = pcnt[off];
      pcnt[off] = (unsigned short)run;
      run += v;
    }
    cnt[d] = run;
  } else {
    cnt[d] = 0;
  }
}

// ---- block-local exclusive scan of 2048-chunks of cnt, in place ----
__global__ void k_scanA(unsigned* __restrict__ cnt, unsigned* __restrict__ bsum) {
  __shared__ unsigned sh[256];
  int tid = threadIdx.x;
  int base = blockIdx.x * 2048 + tid * 8;
  unsigned v[8], tsum = 0;
#pragma unroll
  for (int j = 0; j < 8; j++) { v[j] = cnt[base + j]; tsum += v[j]; }
  sh[tid] = tsum;
  __syncthreads();
  for (int off = 1; off < 256; off <<= 1) {
    unsigned t = (tid >= off) ? sh[tid - off] : 0u;
    __syncthreads();
    sh[tid] += t;
    __syncthreads();
  }
  unsigned run = sh[tid] - tsum;
#pragma unroll
  for (int j = 0; j < 8; j++) { unsigned t = v[j]; cnt[base + j] = run; run += t; }
  if (tid == 255) bsum[blockIdx.x] = sh[255];
}

// ---- add block-prefix (<=24 serial adds per block) ----
__global__ void k_fix(unsigned* __restrict__ cnt, const unsigned* __restrict__ bsum) {
  int blk = blockIdx.x;
  if (blk == 0) return;
  unsigned p = 0;
  for (int k = 0; k < blk; k++) p += bsum[k];
  int base = blk * 2048 + threadIdx.x * 8;
#pragma unroll
  for (int j = 0; j < 8; j++) cnt[base + j] += p;
}

// ---- FUSED dense + fill (r2 mapping: dense blocks [0,NDB) then fill blocks):
// Dense (rels 0..3 only; self-loop lives in k_agg): H[r][n]=xbf[n]@W_r+b_r
// (bf16, LDS-staged nontemporal stores). Fill: scatter edge rowcodes into
// dst-sorted ssrc via pos = cnt[d] + chunk_prefix[e/EPB][d] + rank[e]. No atomics.
// launch_bounds (256,4): VGPR=100 fits 4 waves/EU; lets fill blocks pack 4/CU
// alongside dense early (was capped at 2 blocks/CU).
__global__ __launch_bounds__(256, 4) void k_dfill(
    const unsigned short* __restrict__ xbf, const unsigned short* __restrict__ Wt,
    const float* __restrict__ bias, unsigned short* __restrict__ H,
    const int* __restrict__ rel, const int* __restrict__ dst,
    const int* __restrict__ src, const unsigned* __restrict__ cnt,
    const unsigned short* __restrict__ rank, const unsigned short* __restrict__ pfx,
    unsigned* __restrict__ ssrc) {
  if (blockIdx.x >= NDB) {
    // ---- fill part: pure streaming, no atomics ----
    int e = (blockIdx.x - NDB) * 256 + threadIdx.x;
    if (e < NEDGES) {
      int r = rel[e]; r = r < 0 ? 0 : (r > NRELS - 1 ? NRELS - 1 : r);
      int d = dst[e];
      unsigned pos = cnt[d] + (unsigned)pfx[(size_t)(e / EPB) * NNODES + d] + (unsigned)rank[e];
      ssrc[pos] = (unsigned)(r * NNODES + src[e]);
    }
    return;
  }
  // ---- dense part ----
  __shared__ unsigned short st[4][2048];  // 4 waves x 4 KB tile staging
  int lane = threadIdx.x & 63;
  int wv = threadIdx.x >> 6;
  int r = blockIdx.x / DBLK;              // rel region 0..3
  const int NT = NNODES / 16;             // 3125 row-tiles per rel
  int col = lane & 15, quad = lane >> 4;

  const unsigned short* wr = Wt + (r << 14);
  bf16x8 B[8][4];
  float bs[8];
#pragma unroll
  for (int ct = 0; ct < 8; ct++) {
#pragma unroll
    for (int kk = 0; kk < 4; kk++)
      B[ct][kk] = *(const bf16x8*)(wr + ((ct * 16 + col) << 7) + kk * 32 + quad * 8);
    bs[ct] = bias[(r << 7) + ct * 16 + col];
  }

  for (int t = (blockIdx.x % DBLK) * 4 + wv; t < NT; t += DBLK * 4) {
    int n0 = t * 16;
    int na = n0 + col;
    bf16x8 a0 = *(const bf16x8*)(xbf + (na << 7) + quad * 8);
    bf16x8 a1 = *(const bf16x8*)(xbf + (na << 7) + 32 + quad * 8);
    bf16x8 a2 = *(const bf16x8*)(xbf + (na << 7) + 64 + quad * 8);
    bf16x8 a3 = *(const bf16x8*)(xbf + (na << 7) + 96 + quad * 8);

#pragma unroll
    for (int ct = 0; ct < 8; ct++) {
      f32x4 acc = {0.f, 0.f, 0.f, 0.f};
      acc = __builtin_amdgcn_mfma_f32_16x16x32_bf16(a0, B[ct][0], acc, 0, 0, 0);
      acc = __builtin_amdgcn_mfma_f32_16x16x32_bf16(a1, B[ct][1], acc, 0, 0, 0);
      acc = __builtin_amdgcn_mfma_f32_16x16x32_bf16(a2, B[ct][2], acc, 0, 0, 0);
      acc = __builtin_amdgcn_mfma_f32_16x16x32_bf16(a3, B[ct][3], acc, 0, 0, 0);
      int cc = ct * 16 + col;
#pragma unroll
      for (int j = 0; j < 4; j++) st[wv][(quad * 4 + j) * 128 + cc] = f2bf(acc[j] + bs[ct]);
    }
    // wave-private LDS round-trip (intra-wave lgkmcnt ordering; no __syncthreads)
    // nontemporal: H is 51MB streamed, not re-read in this kernel.
    unsigned short* gb = H + (((size_t)(r * NNODES + n0)) << 7);
#pragma unroll
    for (int s = 0; s < 4; s++) {
      int off = s * 512 + lane * 8;  // u16 units: 4 bursts of 1KB, 16B/lane
      __builtin_nontemporal_store(*(const u16x8*)(&st[wv][off]), (u16x8*)(gb + off));
    }
  }
}

// ---- segment-max + self-loop GEMM, fused; single write of out (no RMW).
// Phase 1: quarter-wave (16 lanes) per node gathers H rows (uint4/lane), 8-row
// clamped batches (max idempotent -> duplicates harmless, and they L2-hit);
// result (or 0 for deg==0) to LDS smax[16][128].
// Phase 2: the block's 16 nodes form one 16x128 @ 128x128 self-loop MFMA tile;
// epilogue adds bias + smax and stores out once, nontemporally.
// launch_bounds (256,8): VGPR=40 <= 64, LDS 8KB -> full 32 waves/CU. The kernel is
// gather-latency-bound (r5: occupancy 49% == the (256,4) cap, MfmaUtil 1%, BW 33%);
// doubling resident waves doubles loads in flight.
__global__ __launch_bounds__(256, 8) void k_agg(
    const unsigned* __restrict__ cnt, const unsigned* __restrict__ ssrc,
    const uint4* __restrict__ H4, const unsigned short* __restrict__ xbf,
    const unsigned short* __restrict__ Wt, const float* __restrict__ bias,
    float* __restrict__ out) {
  __shared__ float smax[16][128];  // 8 KB
  int tid = threadIdx.x;
  int n0 = blockIdx.x * 16;        // grid 3125*16 = 50000 exact

  // ---- phase 1: max-gather ----
  int lane16 = tid & 15;
  int q = tid >> 4;
  int n = n0 + q;
  unsigned base = cnt[n];
  int deg = (int)(cnt[n + 1] - base);
  float init = (deg > 0) ? -3.0e38f : 0.0f;  // deg==0: DGL zero-fill
  float m0 = init, m1 = init, m2 = init, m3 = init;
  float m4 = init, m5 = init, m6 = init, m7 = init;
#define UNP(v)                                          \
  m0 = fmaxf(m0, __uint_as_float((v).x << 16));         \
  m1 = fmaxf(m1, __uint_as_float((v).x & 0xFFFF0000u)); \
  m2 = fmaxf(m2, __uint_as_float((v).y << 16));         \
  m3 = fmaxf(m3, __uint_as_float((v).y & 0xFFFF0000u)); \
  m4 = fmaxf(m4, __uint_as_float((v).z << 16));         \
  m5 = fmaxf(m5, __uint_as_float((v).z & 0xFFFF0000u)); \
  m6 = fmaxf(m6, __uint_as_float((v).w << 16));         \
  m7 = fmaxf(m7, __uint_as_float((v).w & 0xFFFF0000u))
  if (deg > 0) {
    int lim = deg - 1;
    for (int i = 0; i < deg; i += 8) {
      unsigned c0 = ssrc[base + min(i, lim)];
      unsigned c1 = ssrc[base + min(i + 1, lim)];
      unsigned c2 = ssrc[base + min(i + 2, lim)];
      unsigned c3 = ssrc[base + min(i + 3, lim)];
      unsigned c4 = ssrc[base + min(i + 4, lim)];
      unsigned c5 = ssrc[base + min(i + 5, lim)];
      unsigned c6 = ssrc[base + min(i + 6, lim)];
      unsigned c7 = ssrc[base + min(i + 7, lim)];
      uint4 v0 = H4[((size_t)c0 << 4) + lane16];
      uint4 v1 = H4[((size_t)c1 << 4) + lane16];
      uint4 v2 = H4[((size_t)c2 << 4) + lane16];
      uint4 v3 = H4[((size_t)c3 << 4) + lane16];
      uint4 v4 = H4[((size_t)c4 << 4) + lane16];
      uint4 v5 = H4[((size_t)c5 << 4) + lane16];
      uint4 v6 = H4[((size_t)c6 << 4) + lane16];
      uint4 v7 = H4[((size_t)c7 << 4) + lane16];
      UNP(v0); UNP(v1); UNP(v2); UNP(v3);
      UNP(v4); UNP(v5); UNP(v6); UNP(v7);
    }
  }
#undef UNP
  float4* sp = (float4*)&smax[q][lane16 * 8];
  sp[0] = (float4){m0, m1, m2, m3};
  sp[1] = (float4){m4, m5, m6, m7};
  __syncthreads();

  // ---- phase 2: self-loop 16x128 @ 128x128 + combine ----
  int l64 = tid & 63;
  int wv = tid >> 6;
  int col = l64 & 15, quad = l64 >> 4;
  const unsigned short* wr = Wt + (4 << 14);
  int na = n0 + col;
  bf16x8 a0 = *(const bf16x8*)(xbf + (na << 7) + quad * 8);
  bf16x8 a1 = *(const bf16x8*)(xbf + (na << 7) + 32 + quad * 8);
  bf16x8 a2 = *(const bf16x8*)(xbf + (na << 7) + 64 + quad * 8);
  bf16x8 a3 = *(const bf16x8*)(xbf + (na << 7) + 96 + quad * 8);
#pragma unroll
  for (int cti = 0; cti < 2; cti++) {
    int ct = wv * 2 + cti;  // wave wv owns col-tiles 2wv, 2wv+1
    bf16x8 b0 = *(const bf16x8*)(wr + ((ct * 16 + col) << 7) + 0 * 32 + quad * 8);
    bf16x8 b1 = *(const bf16x8*)(wr + ((ct * 16 + col) << 7) + 1 * 32 + quad * 8);
    bf16x8 b2 = *(const bf16x8*)(wr + ((ct * 16 + col) << 7) + 2 * 32 + quad * 8);
    bf16x8 b3 = *(const bf16x8*)(wr + ((ct * 16 + col) << 7) + 3 * 32 + quad * 8);
    float bsv = bias[(4 << 7) + ct * 16 + col];
    f32x4 acc = {0.f, 0.f, 0.f, 0.f};
    acc = __builtin_amdgcn_mfma_f32_16x16x32_bf16(a0, b0, acc, 0, 0, 0);
    acc = __builtin_amdgcn_mfma_f32_16x16x32_bf16(a1, b1, acc, 0, 0, 0);
    acc = __builtin_amdgcn_mfma_f32_16x16x32_bf16(a2, b2, acc, 0, 0, 0);
    acc = __builtin_amdgcn_mfma_f32_16x16x32_bf16(a3, b3, acc, 0, 0, 0);
    int cc = ct * 16 + col;
#pragma unroll
    for (int j = 0; j < 4; j++) {
      int row = quad * 4 + j;
      __builtin_nontemporal_store(acc[j] + bsv + smax[row][cc],
                                  out + ((size_t)(n0 + row) << 7) + (unsigned)cc);
    }
  }
}

extern "C" void kernel_launch(void* const* d_in, const int* in_sizes, int n_in,
                              void* d_out, int out_size, void* d_ws, size_t ws_size,
                              hipStream_t stream) {
  const float* x = (const float*)d_in[0];
  const float* W = (const float*)d_in[1];
  const float* bias = (const float*)d_in[2];
  const int* src = (const int*)d_in[3];
  const int* dst = (const int*)d_in[4];
  const int* rel = (const int*)d_in[5];

  char* ws = (char*)d_ws;
  unsigned* ssrc = (unsigned*)(ws + SSRC_OFF);
  unsigned* cnt = (unsigned*)(ws + CNT_OFF);
  unsigned* bsum = (unsigned*)(ws + BSUM_OFF);
  unsigned short* rank = (unsigned short*)(ws + RANK_OFF);
  unsigned short* pcnt = (unsigned short*)(ws + PCNT_OFF);
  unsigned short* Wt = (unsigned short*)(ws + WT_OFF);
  unsigned short* xbf = (unsigned short*)(ws + XBF_OFF);
  unsigned short* H = (unsigned short*)(ws + H_OFF);
  float* out = (float*)d_out;

  // no memset needed: k_scanC writes every cnt entry, k_ph writes every pcnt entry
  hipLaunchKernelGGL(k_ph, dim3(NHC * 2 + NPB), dim3(1024), 0, stream, x, xbf, W, Wt, dst, rank,
                     pcnt);
  hipLaunchKernelGGL(k_scanC, dim3(200), dim3(256), 0, stream, pcnt, cnt);
  hipLaunchKernelGGL(k_scanA, dim3(NBLK2), dim3(256), 0, stream, cnt, bsum);
  hipLaunchKernelGGL(k_fix, dim3(NBLK2), dim3(256), 0, stream, cnt, bsum);
  hipLaunchKernelGGL(k_dfill, dim3(NDB + NFB), dim3(256), 0, stream, xbf, Wt, bias, H, rel,
                     dst, src, cnt, rank, pcnt, ssrc);
  hipLaunchKernelGGL(k_agg, dim3(3125), dim3(256), 0, stream, cnt, ssrc, (const uint4*)H, xbf,
                     Wt, bias, out);
}

// Round 8
// 182.498 us; speedup vs baseline: 1.1323x; 1.1323x over previous
//
#include <hip/hip_runtime.h>

// Problem constants (fixed by setup_inputs)
#define NNODES 50000
#define NEDGES 800000
#define DIM    128
#define NRELS  4          // edge relations; weight slice 4 = self-loop
#define NBLK2  25         // scan chunks: 25*2048 = 51200 >= NNODES+1
#define DBLK   128        // k_dfill dense blocks per rel (r2 mapping)
#define NDB    (4*DBLK)   // 512 dense blocks (self-loop lives in k_agg)
#define NFB    3125       // fill blocks
#define EPB    12500      // edges per hist chunk
#define NHC    64         // hist chunks (NHC*EPB == NEDGES)
#define RNG    25000      // dst bins per hist range-block (2 ranges cover NNODES)
#define NPB    782        // prep blocks in k_ph (782*1024 >= 800000)

typedef __attribute__((ext_vector_type(8))) short bf16x8;
typedef __attribute__((ext_vector_type(8))) unsigned short u16x8;
typedef __attribute__((ext_vector_type(4))) float f32x4;

// ---- ws layout (bytes) ----
#define SSRC_OFF 0             // u32[NEDGES]: rowcode = rel*NNODES+src, dst-sorted  3,200,000
#define CNT_OFF  3200000       // u32[51200] dst histogram excl scan                   204,800
#define BSUM_OFF 3404800       // u32[64]                                                  256
#define RANK_OFF 3405056       // u16[NEDGES] within-(chunk,dst) rank                1,600,000
#define PCNT_OFF 5005056       // u16[NHC][NNODES] per-chunk hist -> excl col-scan   6,400,000
#define WT_OFF   11405056      // bf16[5*128*128] W^T                                  163,840
#define XBF_OFF  11568896      // bf16[NNODES*DIM]                                  12,800,000
#define H_OFF    24368896      // bf16[4*NNODES*128] per-rel transforms             51,200,000
                               // total ~75.6 MB

__device__ __forceinline__ unsigned short f2bf(float f) {  // RNE f32->bf16
  unsigned u = __float_as_uint(f);
  return (unsigned short)((u + 0x7FFFu + ((u >> 16) & 1u)) >> 16);
}

// ---- FUSED prep + hist (independent roles, disjoint block ranges, co-scheduled):
// Blocks [0, NHC*2): LDS-privatized per-chunk dst histogram + within-chunk rank.
//   25000 bins/range packed 2 x u16 per u32 = 50KB LDS; low field max 12500 so the
//   packed add never carries across fields. No global atomics.
// Blocks [NHC*2, +NPB): x f32->bf16 convert, W transpose+convert (pure BW).
__global__ __launch_bounds__(1024) void k_ph(
    const float* __restrict__ x, unsigned short* __restrict__ xbf,
    const float* __restrict__ W, unsigned short* __restrict__ Wt,
    const int* __restrict__ dst, unsigned short* __restrict__ rank,
    unsigned short* __restrict__ pcnt) {
  __shared__ unsigned lh[RNG / 2];  // 12500 u32 = 50,000 B
  if (blockIdx.x < NHC * 2) {
    int c = blockIdx.x >> 1;
    int r0 = (blockIdx.x & 1) * RNG;
    for (int i = threadIdx.x; i < RNG / 2; i += 1024) lh[i] = 0u;
    __syncthreads();
    int e0 = c * EPB;
    for (int e = e0 + threadIdx.x; e < e0 + EPB; e += 1024) {
      int d = dst[e] - r0;
      if ((unsigned)d < (unsigned)RNG) {
        unsigned old = atomicAdd(&lh[d >> 1], (d & 1) ? 65536u : 1u);
        rank[e] = (unsigned short)((old >> ((d & 1) << 4)) & 0xFFFFu);
      }
    }
    __syncthreads();
    // dump packed u16 pairs: exactly the u16[RNG] slice of row c at offset r0
    unsigned* prow = (unsigned*)(pcnt + (size_t)c * NNODES + r0);
    for (int i = threadIdx.x; i < RNG / 2; i += 1024) prow[i] = lh[i];
    return;
  }
  int i = (blockIdx.x - NHC * 2) * 1024 + threadIdx.x;
  if (i < NNODES * DIM / 8) {
    const float4* p = (const float4*)x + i * 2;
    float4 v0 = p[0], v1 = p[1];
    u16x8 o;
    o[0] = f2bf(v0.x); o[1] = f2bf(v0.y); o[2] = f2bf(v0.z); o[3] = f2bf(v0.w);
    o[4] = f2bf(v1.x); o[5] = f2bf(v1.y); o[6] = f2bf(v1.z); o[7] = f2bf(v1.w);
    *(u16x8*)(xbf + i * 8) = o;
  }
  if (i < 5 * DIM * DIM) {
    int r = i >> 14, rem = i & 16383, k = rem >> 7, c = rem & 127;
    Wt[(r << 14) + (c << 7) + k] = f2bf(W[i]);
  }
}

// ---- wide column-scan: one bin per thread over the NHC chunk rows, in place ->
// exclusive chunk prefix; bin total -> cnt[d]. Bins >= NNODES zeroed so the
// downstream total-scan sees clean tails.
__global__ void k_scanC(unsigned short* __restrict__ pcnt, unsigned* __restrict__ cnt) {
  int d = blockIdx.x * 256 + threadIdx.x;  // grid 200*256 = 51200 exact
  if (d < NNODES) {
    unsigned run = 0;
#pragma unroll 8
    for (int b = 0; b < NHC; b++) {
      size_t off = (size_t)b * NNODES + d;
      unsigned v = pcnt[off];
      pcnt[off] = (unsigned short)run;
      run += v;
    }
    cnt[d] = run;
  } else {
    cnt[d] = 0;
  }
}

// ---- block-local exclusive scan of 2048-chunks of cnt, in place ----
__global__ void k_scanA(unsigned* __restrict__ cnt, unsigned* __restrict__ bsum) {
  __shared__ unsigned sh[256];
  int tid = threadIdx.x;
  int base = blockIdx.x * 2048 + tid * 8;
  unsigned v[8], tsum = 0;
#pragma unroll
  for (int j = 0; j < 8; j++) { v[j] = cnt[base + j]; tsum += v[j]; }
  sh[tid] = tsum;
  __syncthreads();
  for (int off = 1; off < 256; off <<= 1) {
    unsigned t = (tid >= off) ? sh[tid - off] : 0u;
    __syncthreads();
    sh[tid] += t;
    __syncthreads();
  }
  unsigned run = sh[tid] - tsum;
#pragma unroll
  for (int j = 0; j < 8; j++) { unsigned t = v[j]; cnt[base + j] = run; run += t; }
  if (tid == 255) bsum[blockIdx.x] = sh[255];
}

// ---- add block-prefix (<=24 serial adds per block) ----
__global__ void k_fix(unsigned* __restrict__ cnt, const unsigned* __restrict__ bsum) {
  int blk = blockIdx.x;
  if (blk == 0) return;
  unsigned p = 0;
  for (int k = 0; k < blk; k++) p += bsum[k];
  int base = blk * 2048 + threadIdx.x * 8;
#pragma unroll
  for (int j = 0; j < 8; j++) cnt[base + j] += p;
}

// ---- FUSED dense + fill (r2 mapping: dense blocks [0,NDB) then fill blocks):
// Dense (rels 0..3 only; self-loop lives in k_agg): H[r][n]=xbf[n]@W_r+b_r
// (bf16, LDS-staged nontemporal stores). Fill: scatter edge rowcodes into
// dst-sorted ssrc via pos = cnt[d] + chunk_prefix[e/EPB][d] + rank[e]. No atomics.
// launch_bounds MUST stay (256,2): the dense body holds B[8][4] (~128 VGPR of
// fragments); (256,4) capped VGPR at 64 and spilled (r7: FETCH +30MB, dur 48->63).
// Residency is grid-limited in the dense tail, not bounds-limited.
__global__ __launch_bounds__(256, 2) void k_dfill(
    const unsigned short* __restrict__ xbf, const unsigned short* __restrict__ Wt,
    const float* __restrict__ bias, unsigned short* __restrict__ H,
    const int* __restrict__ rel, const int* __restrict__ dst,
    const int* __restrict__ src, const unsigned* __restrict__ cnt,
    const unsigned short* __restrict__ rank, const unsigned short* __restrict__ pfx,
    unsigned* __restrict__ ssrc) {
  if (blockIdx.x >= NDB) {
    // ---- fill part: pure streaming, no atomics ----
    int e = (blockIdx.x - NDB) * 256 + threadIdx.x;
    if (e < NEDGES) {
      int r = rel[e]; r = r < 0 ? 0 : (r > NRELS - 1 ? NRELS - 1 : r);
      int d = dst[e];
      unsigned pos = cnt[d] + (unsigned)pfx[(size_t)(e / EPB) * NNODES + d] + (unsigned)rank[e];
      ssrc[pos] = (unsigned)(r * NNODES + src[e]);
    }
    return;
  }
  // ---- dense part ----
  __shared__ unsigned short st[4][2048];  // 4 waves x 4 KB tile staging
  int lane = threadIdx.x & 63;
  int wv = threadIdx.x >> 6;
  int r = blockIdx.x / DBLK;              // rel region 0..3
  const int NT = NNODES / 16;             // 3125 row-tiles per rel
  int col = lane & 15, quad = lane >> 4;

  const unsigned short* wr = Wt + (r << 14);
  bf16x8 B[8][4];
  float bs[8];
#pragma unroll
  for (int ct = 0; ct < 8; ct++) {
#pragma unroll
    for (int kk = 0; kk < 4; kk++)
      B[ct][kk] = *(const bf16x8*)(wr + ((ct * 16 + col) << 7) + kk * 32 + quad * 8);
    bs[ct] = bias[(r << 7) + ct * 16 + col];
  }

  for (int t = (blockIdx.x % DBLK) * 4 + wv; t < NT; t += DBLK * 4) {
    int n0 = t * 16;
    int na = n0 + col;
    bf16x8 a0 = *(const bf16x8*)(xbf + (na << 7) + quad * 8);
    bf16x8 a1 = *(const bf16x8*)(xbf + (na << 7) + 32 + quad * 8);
    bf16x8 a2 = *(const bf16x8*)(xbf + (na << 7) + 64 + quad * 8);
    bf16x8 a3 = *(const bf16x8*)(xbf + (na << 7) + 96 + quad * 8);

#pragma unroll
    for (int ct = 0; ct < 8; ct++) {
      f32x4 acc = {0.f, 0.f, 0.f, 0.f};
      acc = __builtin_amdgcn_mfma_f32_16x16x32_bf16(a0, B[ct][0], acc, 0, 0, 0);
      acc = __builtin_amdgcn_mfma_f32_16x16x32_bf16(a1, B[ct][1], acc, 0, 0, 0);
      acc = __builtin_amdgcn_mfma_f32_16x16x32_bf16(a2, B[ct][2], acc, 0, 0, 0);
      acc = __builtin_amdgcn_mfma_f32_16x16x32_bf16(a3, B[ct][3], acc, 0, 0, 0);
      int cc = ct * 16 + col;
#pragma unroll
      for (int j = 0; j < 4; j++) st[wv][(quad * 4 + j) * 128 + cc] = f2bf(acc[j] + bs[ct]);
    }
    // wave-private LDS round-trip (intra-wave lgkmcnt ordering; no __syncthreads)
    // nontemporal: H is 51MB streamed, not re-read in this kernel.
    unsigned short* gb = H + (((size_t)(r * NNODES + n0)) << 7);
#pragma unroll
    for (int s = 0; s < 4; s++) {
      int off = s * 512 + lane * 8;  // u16 units: 4 bursts of 1KB, 16B/lane
      __builtin_nontemporal_store(*(const u16x8*)(&st[wv][off]), (u16x8*)(gb + off));
    }
  }
}

// ---- segment-max + self-loop GEMM, fused; single write of out (no RMW).
// Phase 1: quarter-wave (16 lanes) per node gathers H rows (uint4/lane), 8-row
// clamped batches (max idempotent -> duplicates harmless, and they L2-hit);
// result (or 0 for deg==0) to LDS smax[16][128].
// Phase 2: the block's 16 nodes form one 16x128 @ 128x128 self-loop MFMA tile;
// epilogue adds bias + smax and stores out once, nontemporally.
// launch_bounds (256,8): VGPR=40 <= 64, LDS 8KB -> full 32 waves/CU. The kernel is
// gather-latency-bound (r5: occupancy 49% == the (256,4) cap, MfmaUtil 1%, BW 33%);
// doubling resident waves doubles loads in flight.
__global__ __launch_bounds__(256, 8) void k_agg(
    const unsigned* __restrict__ cnt, const unsigned* __restrict__ ssrc,
    const uint4* __restrict__ H4, const unsigned short* __restrict__ xbf,
    const unsigned short* __restrict__ Wt, const float* __restrict__ bias,
    float* __restrict__ out) {
  __shared__ float smax[16][128];  // 8 KB
  int tid = threadIdx.x;
  int n0 = blockIdx.x * 16;        // grid 3125*16 = 50000 exact

  // ---- phase 1: max-gather ----
  int lane16 = tid & 15;
  int q = tid >> 4;
  int n = n0 + q;
  unsigned base = cnt[n];
  int deg = (int)(cnt[n + 1] - base);
  float init = (deg > 0) ? -3.0e38f : 0.0f;  // deg==0: DGL zero-fill
  float m0 = init, m1 = init, m2 = init, m3 = init;
  float m4 = init, m5 = init, m6 = init, m7 = init;
#define UNP(v)                                          \
  m0 = fmaxf(m0, __uint_as_float((v).x << 16));         \
  m1 = fmaxf(m1, __uint_as_float((v).x & 0xFFFF0000u)); \
  m2 = fmaxf(m2, __uint_as_float((v).y << 16));         \
  m3 = fmaxf(m3, __uint_as_float((v).y & 0xFFFF0000u)); \
  m4 = fmaxf(m4, __uint_as_float((v).z << 16));         \
  m5 = fmaxf(m5, __uint_as_float((v).z & 0xFFFF0000u)); \
  m6 = fmaxf(m6, __uint_as_float((v).w << 16));         \
  m7 = fmaxf(m7, __uint_as_float((v).w & 0xFFFF0000u))
  if (deg > 0) {
    int lim = deg - 1;
    for (int i = 0; i < deg; i += 8) {
      unsigned c0 = ssrc[base + min(i, lim)];
      unsigned c1 = ssrc[base + min(i + 1, lim)];
      unsigned c2 = ssrc[base + min(i + 2, lim)];
      unsigned c3 = ssrc[base + min(i + 3, lim)];
      unsigned c4 = ssrc[base + min(i + 4, lim)];
      unsigned c5 = ssrc[base + min(i + 5, lim)];
      unsigned c6 = ssrc[base + min(i + 6, lim)];
      unsigned c7 = ssrc[base + min(i + 7, lim)];
      uint4 v0 = H4[((size_t)c0 << 4) + lane16];
      uint4 v1 = H4[((size_t)c1 << 4) + lane16];
      uint4 v2 = H4[((size_t)c2 << 4) + lane16];
      uint4 v3 = H4[((size_t)c3 << 4) + lane16];
      uint4 v4 = H4[((size_t)c4 << 4) + lane16];
      uint4 v5 = H4[((size_t)c5 << 4) + lane16];
      uint4 v6 = H4[((size_t)c6 << 4) + lane16];
      uint4 v7 = H4[((size_t)c7 << 4) + lane16];
      UNP(v0); UNP(v1); UNP(v2); UNP(v3);
      UNP(v4); UNP(v5); UNP(v6); UNP(v7);
    }
  }
#undef UNP
  float4* sp = (float4*)&smax[q][lane16 * 8];
  sp[0] = (float4){m0, m1, m2, m3};
  sp[1] = (float4){m4, m5, m6, m7};
  __syncthreads();

  // ---- phase 2: self-loop 16x128 @ 128x128 + combine ----
  int l64 = tid & 63;
  int wv = tid >> 6;
  int col = l64 & 15, quad = l64 >> 4;
  const unsigned short* wr = Wt + (4 << 14);
  int na = n0 + col;
  bf16x8 a0 = *(const bf16x8*)(xbf + (na << 7) + quad * 8);
  bf16x8 a1 = *(const bf16x8*)(xbf + (na << 7) + 32 + quad * 8);
  bf16x8 a2 = *(const bf16x8*)(xbf + (na << 7) + 64 + quad * 8);
  bf16x8 a3 = *(const bf16x8*)(xbf + (na << 7) + 96 + quad * 8);
#pragma unroll
  for (int cti = 0; cti < 2; cti++) {
    int ct = wv * 2 + cti;  // wave wv owns col-tiles 2wv, 2wv+1
    bf16x8 b0 = *(const bf16x8*)(wr + ((ct * 16 + col) << 7) + 0 * 32 + quad * 8);
    bf16x8 b1 = *(const bf16x8*)(wr + ((ct * 16 + col) << 7) + 1 * 32 + quad * 8);
    bf16x8 b2 = *(const bf16x8*)(wr + ((ct * 16 + col) << 7) + 2 * 32 + quad * 8);
    bf16x8 b3 = *(const bf16x8*)(wr + ((ct * 16 + col) << 7) + 3 * 32 + quad * 8);
    float bsv = bias[(4 << 7) + ct * 16 + col];
    f32x4 acc = {0.f, 0.f, 0.f, 0.f};
    acc = __builtin_amdgcn_mfma_f32_16x16x32_bf16(a0, b0, acc, 0, 0, 0);
    acc = __builtin_amdgcn_mfma_f32_16x16x32_bf16(a1, b1, acc, 0, 0, 0);
    acc = __builtin_amdgcn_mfma_f32_16x16x32_bf16(a2, b2, acc, 0, 0, 0);
    acc = __builtin_amdgcn_mfma_f32_16x16x32_bf16(a3, b3, acc, 0, 0, 0);
    int cc = ct * 16 + col;
#pragma unroll
    for (int j = 0; j < 4; j++) {
      int row = quad * 4 + j;
      __builtin_nontemporal_store(acc[j] + bsv + smax[row][cc],
                                  out + ((size_t)(n0 + row) << 7) + (unsigned)cc);
    }
  }
}

extern "C" void kernel_launch(void* const* d_in, const int* in_sizes, int n_in,
                              void* d_out, int out_size, void* d_ws, size_t ws_size,
                              hipStream_t stream) {
  const float* x = (const float*)d_in[0];
  const float* W = (const float*)d_in[1];
  const float* bias = (const float*)d_in[2];
  const int* src = (const int*)d_in[3];
  const int* dst = (const int*)d_in[4];
  const int* rel = (const int*)d_in[5];

  char* ws = (char*)d_ws;
  unsigned* ssrc = (unsigned*)(ws + SSRC_OFF);
  unsigned* cnt = (unsigned*)(ws + CNT_OFF);
  unsigned* bsum = (unsigned*)(ws + BSUM_OFF);
  unsigned short* rank = (unsigned short*)(ws + RANK_OFF);
  unsigned short* pcnt = (unsigned short*)(ws + PCNT_OFF);
  unsigned short* Wt = (unsigned short*)(ws + WT_OFF);
  unsigned short* xbf = (unsigned short*)(ws + XBF_OFF);
  unsigned short* H = (unsigned short*)(ws + H_OFF);
  float* out = (float*)d_out;

  // no memset needed: k_scanC writes every cnt entry, k_ph writes every pcnt entry
  hipLaunchKernelGGL(k_ph, dim3(NHC * 2 + NPB), dim3(1024), 0, stream, x, xbf, W, Wt, dst, rank,
                     pcnt);
  hipLaunchKernelGGL(k_scanC, dim3(200), dim3(256), 0, stream, pcnt, cnt);
  hipLaunchKernelGGL(k_scanA, dim3(NBLK2), dim3(256), 0, stream, cnt, bsum);
  hipLaunchKernelGGL(k_fix, dim3(NBLK2), dim3(256), 0, stream, cnt, bsum);
  hipLaunchKernelGGL(k_dfill, dim3(NDB + NFB), dim3(256), 0, stream, xbf, Wt, bias, H, rel,
                     dst, src, cnt, rank, pcnt, ssrc);
  hipLaunchKernelGGL(k_agg, dim3(3125), dim3(256), 0, stream, cnt, ssrc, (const uint4*)H, xbf,
                     Wt, bias, out);
}